// Round 5
// baseline (135.305 us; speedup 1.0000x reference)
//
#include <hip/hip_runtime.h>
#include <stdint.h>
#include <math.h>

#define D_MODEL 1024
#define NUM_HEADS 16
#define D_K 64
#define SEQ 2048
#define BATCH 2
#define SIM_THRESH 0.7f

#define TS 64          // tile size (square)
#define BK 64          // K chunk
#define NIT (D_MODEL / BK)   // 16

#define NROWS (BATCH * SEQ)                       // 4096
#define VP_BLOCKS ((NROWS / TS) * (D_MODEL / TS)) // 64*16 = 1024
#define SIM_ROWB (SEQ / TS)                       // 32
#define SIM_TRI (SIM_ROWB * (SIM_ROWB + 1) / 2)   // 528
#define SIM_BLOCKS (SIM_TRI * BATCH)              // 1056
#define GRID (VP_BLOCKS + SIM_BLOCKS)             // 2080

#define TILE_SH (TS * BK)    // 4096 shorts = 8 KB

typedef __attribute__((ext_vector_type(8))) short bf16x8;
typedef __attribute__((ext_vector_type(4))) float f32x4;

static __device__ __forceinline__ unsigned short f2bf(float f) {
    unsigned int u = __float_as_uint(f);
    unsigned int r = (u + 0x7FFF + ((u >> 16) & 1)) >> 16;   // RNE
    return (unsigned short)r;
}
static __device__ __forceinline__ float bf2f(unsigned short u) {
    return __uint_as_float(((unsigned int)u) << 16);
}

// ---------- L1: normalize x rows -> bf16 (+norms, zero cnt)  AND  cast Wv -> bf16 ----------
__global__ __launch_bounds__(256) void k_prep(const float* __restrict__ x,
                                              const float* __restrict__ Wv,
                                              unsigned short* __restrict__ xn,
                                              unsigned short* __restrict__ Wvb,
                                              float* __restrict__ norms,
                                              int* __restrict__ cnt) {
    int bid = blockIdx.x, tid = threadIdx.x;
    if (bid < NROWS) {
        const float4* xr = (const float4*)(x + (size_t)bid * D_MODEL);
        float4 vv = xr[tid];
        float ss = vv.x * vv.x + vv.y * vv.y + vv.z * vv.z + vv.w * vv.w;
        for (int off = 32; off > 0; off >>= 1) ss += __shfl_down(ss, off, 64);
        __shared__ float wsum[4];
        int lane = tid & 63, wv = tid >> 6;
        if (lane == 0) wsum[wv] = ss;
        __syncthreads();
        float nrm = sqrtf(wsum[0] + wsum[1] + wsum[2] + wsum[3]);
        float inv = 1.0f / fmaxf(nrm, 1e-12f);
        ushort4 o;
        o.x = f2bf(vv.x * inv); o.y = f2bf(vv.y * inv);
        o.z = f2bf(vv.z * inv); o.w = f2bf(vv.w * inv);
        *(ushort4*)(xn + (size_t)bid * D_MODEL + tid * 4) = o;
        if (tid == 0) { norms[bid] = nrm; cnt[bid] = 0; }
    } else {
        size_t i = (size_t)(bid - NROWS) * 256 + tid;   // float4 chunk index
        float4 w = ((const float4*)Wv)[i];
        ushort4 o;
        o.x = f2bf(w.x); o.y = f2bf(w.y); o.z = f2bf(w.z); o.w = f2bf(w.w);
        *(ushort4*)(Wvb + i * 4) = o;
    }
}

// ---------- staging: 64x64 bf16 tile global -> LDS, 16B/lane async ----------
static __device__ __forceinline__ void stage64(const unsigned short* __restrict__ gsrc,
                                               int rowBase, int kk,
                                               short* ldsDst, int tid) {
#pragma unroll
    for (int p = 0; p < 2; ++p) {
        int idx = p * 256 + tid;        // 0..511 chunks of 16B
        int row = idx >> 3;             // 0..63
        int ch  = idx & 7;              // 0..7
        const unsigned short* ga = gsrc + (size_t)(rowBase + row) * D_MODEL + kk + ch * 8;
        __builtin_amdgcn_global_load_lds(
            (const __attribute__((address_space(1))) unsigned int*)ga,
            (__attribute__((address_space(3))) unsigned int*)(ldsDst + idx * 8),
            16, 0, 0);
    }
}

// ---------- L2: fused V-proj (blocks 0..1023) + symmetric sim/count (1024..2079) ----------
// 64x64 tiles, BK=64, double-buffered LDS. 4 waves as 2x2, each wave a 32x32 micro-tile.
__global__ __launch_bounds__(256) void k_main(const unsigned short* __restrict__ xn,
                                              const unsigned short* __restrict__ Wvb,
                                              const float* __restrict__ bv,
                                              const float* __restrict__ norms,
                                              float* __restrict__ v,
                                              int* __restrict__ cnt,
                                              float* __restrict__ out) {
    __shared__ short As[2 * TILE_SH];
    __shared__ short Bs[2 * TILE_SH];
    int bid = blockIdx.x;
    int tid = threadIdx.x;
    int lane = tid & 63, wave = tid >> 6;
    int wm = wave & 1, wn = wave >> 1;
    int lrow = lane & 15, quad = lane >> 4;

    const unsigned short* Asrc;
    const unsigned short* Bsrc;
    int rowBase, colBase;
    bool isV;
    int b = 0, bi = 0, bj = 0;
    if (bid < VP_BLOCKS) {
        isV = true;
        rowBase = (bid >> 4) * TS;      // 64 row-blocks
        colBase = (bid & 15) * TS;      // 16 col-blocks
        Asrc = xn;
        Bsrc = Wvb;
    } else {
        isV = false;
        int sidx = bid - VP_BLOCKS;
        b = (sidx >= SIM_TRI) ? 1 : 0;
        int r = sidx - b * SIM_TRI;
        bi = 0;
        while (r >= SIM_ROWB - bi) { r -= SIM_ROWB - bi; ++bi; }
        bj = bi + r;
        rowBase = bi * TS;              // batch-local
        colBase = bj * TS;
        Asrc = xn + (size_t)b * SEQ * D_MODEL;
        Bsrc = Asrc;
    }

    int aoff[2], boff[2];
#pragma unroll
    for (int i = 0; i < 2; ++i) {
        aoff[i] = (wm * 32 + i * 16 + lrow) * BK + quad * 8;
        boff[i] = (wn * 32 + i * 16 + lrow) * BK + quad * 8;
    }
    f32x4 acc[2][2] = {};

    stage64(Asrc, rowBase, 0, As, tid);
    stage64(Bsrc, colBase, 0, Bs, tid);
    __syncthreads();
    for (int it = 0; it < NIT; ++it) {
        int cur = it & 1, nxt = cur ^ 1;
        if (it + 1 < NIT) {   // prefetch next K chunk into the other buffer
            stage64(Asrc, rowBase, (it + 1) * BK, As + nxt * TILE_SH, tid);
            stage64(Bsrc, colBase, (it + 1) * BK, Bs + nxt * TILE_SH, tid);
        }
        const short* Ac = As + cur * TILE_SH;
        const short* Bc = Bs + cur * TILE_SH;
#pragma unroll
        for (int kb = 0; kb < 2; ++kb) {
            bf16x8 av[2], bvv[2];
#pragma unroll
            for (int i = 0; i < 2; ++i) av[i]  = *(const bf16x8*)(Ac + aoff[i] + kb * 32);
#pragma unroll
            for (int i = 0; i < 2; ++i) bvv[i] = *(const bf16x8*)(Bc + boff[i] + kb * 32);
#pragma unroll
            for (int mt = 0; mt < 2; ++mt)
#pragma unroll
                for (int nt = 0; nt < 2; ++nt)
                    acc[mt][nt] = __builtin_amdgcn_mfma_f32_16x16x32_bf16(av[mt], bvv[nt], acc[mt][nt], 0, 0, 0);
        }
        __syncthreads();
    }

    if (isV) {
#pragma unroll
        for (int mt = 0; mt < 2; ++mt) {
#pragma unroll
            for (int nt = 0; nt < 2; ++nt) {
                int n = colBase + wn * 32 + nt * 16 + lrow;
                float bn = bv[n];
                int h = n >> 6, j = n & 63;
#pragma unroll
                for (int r = 0; r < 4; ++r) {
                    int m = rowBase + wm * 32 + mt * 16 + quad * 4 + r;
                    float val = acc[mt][nt][r] * norms[m] + bn;
                    v[(size_t)m * D_MODEL + n] = val;
                    int bb = m >> 11, s = m & (SEQ - 1);
                    out[(((size_t)(bb * NUM_HEADS + h)) * SEQ + s) * D_K + j] = val;
                }
            }
        }
    } else {
        int* cb = cnt + b * SEQ;
        bool diag = (bi == bj);
#pragma unroll
        for (int mt = 0; mt < 2; ++mt) {
#pragma unroll
            for (int nt = 0; nt < 2; ++nt) {
                int n = colBase + wn * 32 + nt * 16 + lrow;
#pragma unroll
                for (int r = 0; r < 4; ++r) {
                    int m = rowBase + wm * 32 + mt * 16 + quad * 4 + r;
                    if (acc[mt][nt][r] > SIM_THRESH) {
                        atomicAdd(&cb[m], 1);
                        if (!diag) atomicAdd(&cb[n], 1);
                    }
                }
            }
        }
    }
}

// ---------- L3: fix rows with cnt != 1 (cold; cnt==1 rows already hold out = v row) ----------
__global__ __launch_bounds__(256) void k_fix(
    const float* __restrict__ x,
    const float* __restrict__ Wq, const float* __restrict__ bq,
    const float* __restrict__ Wk, const float* __restrict__ bk,
    const float* __restrict__ v,
    const unsigned short* __restrict__ xn,
    const int* __restrict__ cnt,
    float* __restrict__ out)
{
    int tid = threadIdx.x;
    int rowBase = blockIdx.x * 256;

    __shared__ int list[256];
    __shared__ int nlist;
    if (tid == 0) nlist = 0;
    __syncthreads();
    int grow = rowBase + tid;
    if (cnt[grow] != 1) { int p = atomicAdd(&nlist, 1); list[p] = grow; }
    __syncthreads();
    int nfix = nlist;
    if (nfix == 0) return;

    __shared__ uint8_t mrow[SEQ];
    __shared__ float q_row[D_MODEL];
    __shared__ float k_row[D_MODEL];
    __shared__ float accO[D_MODEL];
    __shared__ float m_h[NUM_HEADS], l_h[NUM_HEADS], alpha_h[NUM_HEADS], p_h[NUM_HEADS];

    for (int li = 0; li < nfix; ++li) {
        int row = list[li];
        int b = row >> 11, s = row & (SEQ - 1);

        const unsigned short* xs = xn + (size_t)row * D_MODEL;
        for (int t = tid; t < SEQ; t += 256) {
            const unsigned short* xt = xn + ((size_t)b * SEQ + t) * D_MODEL;
            float d = 0.f;
            for (int k = 0; k < D_MODEL; ++k) d += bf2f(xs[k]) * bf2f(xt[k]);
            mrow[t] = (d > SIM_THRESH) ? 1 : 0;
        }

        const float* xrow = x + (size_t)row * D_MODEL;
        for (int c = tid; c < D_MODEL; c += 256) {
            const float* w = Wq + (size_t)c * D_MODEL;
            float acc = bq[c];
            for (int d = 0; d < D_MODEL; ++d) acc += xrow[d] * w[d];
            q_row[c] = acc;
            accO[c] = 0.f;
        }
        if (tid < NUM_HEADS) { m_h[tid] = -INFINITY; l_h[tid] = 0.f; }
        __syncthreads();

        for (int t = 0; t < SEQ; ++t) {
            if (!mrow[t]) continue;
            const float* xt = x + ((size_t)b * SEQ + t) * D_MODEL;
            for (int c = tid; c < D_MODEL; c += 256) {
                const float* w = Wk + (size_t)c * D_MODEL;
                float acc = bk[c];
                for (int d = 0; d < D_MODEL; ++d) acc += xt[d] * w[d];
                k_row[c] = acc;
            }
            __syncthreads();
            if (tid < NUM_HEADS) {
                float sc = 0.f;
                for (int j = 0; j < D_K; ++j) sc += q_row[tid * D_K + j] * k_row[tid * D_K + j];
                sc *= 0.125f;
                float mnew = fmaxf(m_h[tid], sc);
                float alpha = expf(m_h[tid] - mnew);
                float p = expf(sc - mnew);
                l_h[tid] = l_h[tid] * alpha + p;
                m_h[tid] = mnew;
                alpha_h[tid] = alpha;
                p_h[tid] = p;
            }
            __syncthreads();
            const float* vt = v + ((size_t)b * SEQ + t) * D_MODEL;
            for (int c = tid; c < D_MODEL; c += 256) {
                int h = c >> 6;
                accO[c] = accO[c] * alpha_h[h] + p_h[h] * vt[c];
            }
            __syncthreads();
        }
        for (int c = tid; c < D_MODEL; c += 256) {
            int h = c >> 6, j = c & 63;
            out[(((size_t)(b * NUM_HEADS + h)) * SEQ + s) * D_K + j] = accO[c] / l_h[h];
        }
        __syncthreads();
    }
}

extern "C" void kernel_launch(void* const* d_in, const int* in_sizes, int n_in,
                              void* d_out, int out_size, void* d_ws, size_t ws_size,
                              hipStream_t stream) {
    const float* x  = (const float*)d_in[0];
    const float* Wq = (const float*)d_in[1];
    const float* bq = (const float*)d_in[2];
    const float* Wk = (const float*)d_in[3];
    const float* bk = (const float*)d_in[4];
    const float* Wv = (const float*)d_in[5];
    const float* bv = (const float*)d_in[6];
    float* out = (float*)d_out;

    // workspace: xn bf16 (8MB) | Wvb bf16 (2MB) | v fp32 (16MB) | norms (16KB) | cnt (16KB)
    unsigned short* xn  = (unsigned short*)d_ws;
    unsigned short* Wvb = xn + (size_t)NROWS * D_MODEL;
    float* v     = (float*)(Wvb + (size_t)D_MODEL * D_MODEL);
    float* norms = v + (size_t)NROWS * D_MODEL;
    int* cnt     = (int*)(norms + NROWS);

    // L1: 4096 row-normalize blocks + 1024 Wv-cast blocks
    k_prep<<<NROWS + D_MODEL * D_MODEL / 1024, 256, 0, stream>>>(x, Wv, xn, Wvb, norms, cnt);

    // L2: 1024 vproj blocks + 1056 sim blocks
    k_main<<<GRID, 256, 0, stream>>>(xn, Wvb, bv, norms, v, cnt, out);

    // L3: fix non-singleton rows (cold)
    k_fix<<<NROWS / 256, 256, 0, stream>>>(x, Wq, bq, Wk, bk, v, xn, cnt, out);
}

// Round 6
// 126.435 us; speedup vs baseline: 1.0702x; 1.0702x over previous
//
#include <hip/hip_runtime.h>
#include <stdint.h>
#include <math.h>

#define D_MODEL 1024
#define NUM_HEADS 16
#define D_K 64
#define SEQ 2048
#define BATCH 2
#define SIM_THRESH 0.7f

#define TS 64          // tile size (square)
#define BK 32          // K chunk: 64B LDS row stride -> 2-way bank alias (free)
#define NIT (D_MODEL / BK)   // 32

#define NROWS (BATCH * SEQ)                       // 4096
#define VP_BLOCKS ((NROWS / TS) * (D_MODEL / TS)) // 64*16 = 1024
#define SIM_ROWB (SEQ / TS)                       // 32
#define SIM_TRI (SIM_ROWB * (SIM_ROWB + 1) / 2)   // 528
#define SIM_BLOCKS (SIM_TRI * BATCH)              // 1056
#define GRID (VP_BLOCKS + SIM_BLOCKS)             // 2080

#define TILE_SH (TS * BK)    // 2048 shorts = 4 KB

typedef __attribute__((ext_vector_type(8))) short bf16x8;
typedef __attribute__((ext_vector_type(4))) float f32x4;

static __device__ __forceinline__ unsigned short f2bf(float f) {
    unsigned int u = __float_as_uint(f);
    unsigned int r = (u + 0x7FFF + ((u >> 16) & 1)) >> 16;   // RNE
    return (unsigned short)r;
}
static __device__ __forceinline__ float bf2f(unsigned short u) {
    return __uint_as_float(((unsigned int)u) << 16);
}

// ---------- L1: normalize x rows -> bf16 (+norms, zero cnt)  AND  cast Wv -> bf16 ----------
__global__ __launch_bounds__(256) void k_prep(const float* __restrict__ x,
                                              const float* __restrict__ Wv,
                                              unsigned short* __restrict__ xn,
                                              unsigned short* __restrict__ Wvb,
                                              float* __restrict__ norms,
                                              int* __restrict__ cnt) {
    int bid = blockIdx.x, tid = threadIdx.x;
    if (bid < NROWS) {
        const float4* xr = (const float4*)(x + (size_t)bid * D_MODEL);
        float4 vv = xr[tid];
        float ss = vv.x * vv.x + vv.y * vv.y + vv.z * vv.z + vv.w * vv.w;
        for (int off = 32; off > 0; off >>= 1) ss += __shfl_down(ss, off, 64);
        __shared__ float wsum[4];
        int lane = tid & 63, wv = tid >> 6;
        if (lane == 0) wsum[wv] = ss;
        __syncthreads();
        float nrm = sqrtf(wsum[0] + wsum[1] + wsum[2] + wsum[3]);
        float inv = 1.0f / fmaxf(nrm, 1e-12f);
        ushort4 o;
        o.x = f2bf(vv.x * inv); o.y = f2bf(vv.y * inv);
        o.z = f2bf(vv.z * inv); o.w = f2bf(vv.w * inv);
        *(ushort4*)(xn + (size_t)bid * D_MODEL + tid * 4) = o;
        if (tid == 0) { norms[bid] = nrm; cnt[bid] = 0; }
    } else {
        size_t i = (size_t)(bid - NROWS) * 256 + tid;   // float4 chunk index
        float4 w = ((const float4*)Wv)[i];
        ushort4 o;
        o.x = f2bf(w.x); o.y = f2bf(w.y); o.z = f2bf(w.z); o.w = f2bf(w.w);
        *(ushort4*)(Wvb + i * 4) = o;
    }
}

// ---------- staging: 64x32 bf16 tile global -> LDS, 16B/lane async (1 inst/thread) ----------
static __device__ __forceinline__ void stage64x32(const unsigned short* __restrict__ gsrc,
                                                  int rowBase, int kk,
                                                  short* ldsDst, int tid) {
    int row = tid >> 2;             // 0..63
    int ch  = tid & 3;              // 0..3  (4 x 16B chunks per 64B row)
    const unsigned short* ga = gsrc + (size_t)(rowBase + row) * D_MODEL + kk + ch * 8;
    __builtin_amdgcn_global_load_lds(
        (const __attribute__((address_space(1))) unsigned int*)ga,
        (__attribute__((address_space(3))) unsigned int*)(ldsDst + tid * 8),
        16, 0, 0);
}

// ---------- L2: fused V-proj (blocks 0..1023) + symmetric sim/count (1024..2079) ----------
// 64x64 tiles, BK=32, double-buffered LDS (16 KB). 4 waves as 2x2, 32x32 per wave.
__global__ __launch_bounds__(256) void k_main(const unsigned short* __restrict__ xn,
                                              const unsigned short* __restrict__ Wvb,
                                              const float* __restrict__ bv,
                                              const float* __restrict__ norms,
                                              float* __restrict__ v,
                                              int* __restrict__ cnt,
                                              float* __restrict__ out) {
    __shared__ short As[2 * TILE_SH];
    __shared__ short Bs[2 * TILE_SH];
    int bid = blockIdx.x;
    int tid = threadIdx.x;
    int lane = tid & 63, wave = tid >> 6;
    int wm = wave & 1, wn = wave >> 1;
    int lrow = lane & 15, quad = lane >> 4;

    const unsigned short* Asrc;
    const unsigned short* Bsrc;
    int rowBase, colBase;
    bool isV;
    int b = 0, bi = 0, bj = 0;
    if (bid < VP_BLOCKS) {
        isV = true;
        rowBase = (bid >> 4) * TS;      // 64 row-blocks
        colBase = (bid & 15) * TS;      // 16 col-blocks
        Asrc = xn;
        Bsrc = Wvb;
    } else {
        isV = false;
        int sidx = bid - VP_BLOCKS;
        b = (sidx >= SIM_TRI) ? 1 : 0;
        int r = sidx - b * SIM_TRI;
        bi = 0;
        while (r >= SIM_ROWB - bi) { r -= SIM_ROWB - bi; ++bi; }
        bj = bi + r;
        rowBase = bi * TS;              // batch-local
        colBase = bj * TS;
        Asrc = xn + (size_t)b * SEQ * D_MODEL;
        Bsrc = Asrc;
    }

    int aoff[2], boff[2];
#pragma unroll
    for (int i = 0; i < 2; ++i) {
        aoff[i] = (wm * 32 + i * 16 + lrow) * BK + quad * 8;
        boff[i] = (wn * 32 + i * 16 + lrow) * BK + quad * 8;
    }
    f32x4 acc[2][2] = {};

    stage64x32(Asrc, rowBase, 0, As, tid);
    stage64x32(Bsrc, colBase, 0, Bs, tid);
    __syncthreads();
    for (int it = 0; it < NIT; ++it) {
        int cur = it & 1, nxt = cur ^ 1;
        if (it + 1 < NIT) {   // prefetch next K chunk into the other buffer
            stage64x32(Asrc, rowBase, (it + 1) * BK, As + nxt * TILE_SH, tid);
            stage64x32(Bsrc, colBase, (it + 1) * BK, Bs + nxt * TILE_SH, tid);
        }
        const short* Ac = As + cur * TILE_SH;
        const short* Bc = Bs + cur * TILE_SH;
        bf16x8 av[2], bvv[2];
#pragma unroll
        for (int i = 0; i < 2; ++i) av[i]  = *(const bf16x8*)(Ac + aoff[i]);
#pragma unroll
        for (int i = 0; i < 2; ++i) bvv[i] = *(const bf16x8*)(Bc + boff[i]);
#pragma unroll
        for (int mt = 0; mt < 2; ++mt)
#pragma unroll
            for (int nt = 0; nt < 2; ++nt)
                acc[mt][nt] = __builtin_amdgcn_mfma_f32_16x16x32_bf16(av[mt], bvv[nt], acc[mt][nt], 0, 0, 0);
        __syncthreads();
    }

    if (isV) {
#pragma unroll
        for (int mt = 0; mt < 2; ++mt) {
#pragma unroll
            for (int nt = 0; nt < 2; ++nt) {
                int n = colBase + wn * 32 + nt * 16 + lrow;
                float bn = bv[n];
                int h = n >> 6, j = n & 63;
#pragma unroll
                for (int r = 0; r < 4; ++r) {
                    int m = rowBase + wm * 32 + mt * 16 + quad * 4 + r;
                    float val = acc[mt][nt][r] * norms[m] + bn;
                    v[(size_t)m * D_MODEL + n] = val;
                    int bb = m >> 11, s = m & (SEQ - 1);
                    out[(((size_t)(bb * NUM_HEADS + h)) * SEQ + s) * D_K + j] = val;
                }
            }
        }
    } else {
        int* cb = cnt + b * SEQ;
        bool diag = (bi == bj);
#pragma unroll
        for (int mt = 0; mt < 2; ++mt) {
#pragma unroll
            for (int nt = 0; nt < 2; ++nt) {
                int n = colBase + wn * 32 + nt * 16 + lrow;
#pragma unroll
                for (int r = 0; r < 4; ++r) {
                    int m = rowBase + wm * 32 + mt * 16 + quad * 4 + r;
                    if (acc[mt][nt][r] > SIM_THRESH) {
                        atomicAdd(&cb[m], 1);
                        if (!diag) atomicAdd(&cb[n], 1);
                    }
                }
            }
        }
    }
}

// ---------- L3: fix rows with cnt != 1 (cold; cnt==1 rows already hold out = v row) ----------
__global__ __launch_bounds__(256) void k_fix(
    const float* __restrict__ x,
    const float* __restrict__ Wq, const float* __restrict__ bq,
    const float* __restrict__ Wk, const float* __restrict__ bk,
    const float* __restrict__ v,
    const unsigned short* __restrict__ xn,
    const int* __restrict__ cnt,
    float* __restrict__ out)
{
    int tid = threadIdx.x;
    int rowBase = blockIdx.x * 256;

    __shared__ int list[256];
    __shared__ int nlist;
    if (tid == 0) nlist = 0;
    __syncthreads();
    int grow = rowBase + tid;
    if (cnt[grow] != 1) { int p = atomicAdd(&nlist, 1); list[p] = grow; }
    __syncthreads();
    int nfix = nlist;
    if (nfix == 0) return;

    __shared__ uint8_t mrow[SEQ];
    __shared__ float q_row[D_MODEL];
    __shared__ float k_row[D_MODEL];
    __shared__ float accO[D_MODEL];
    __shared__ float m_h[NUM_HEADS], l_h[NUM_HEADS], alpha_h[NUM_HEADS], p_h[NUM_HEADS];

    for (int li = 0; li < nfix; ++li) {
        int row = list[li];
        int b = row >> 11, s = row & (SEQ - 1);

        const unsigned short* xs = xn + (size_t)row * D_MODEL;
        for (int t = tid; t < SEQ; t += 256) {
            const unsigned short* xt = xn + ((size_t)b * SEQ + t) * D_MODEL;
            float d = 0.f;
            for (int k = 0; k < D_MODEL; ++k) d += bf2f(xs[k]) * bf2f(xt[k]);
            mrow[t] = (d > SIM_THRESH) ? 1 : 0;
        }

        const float* xrow = x + (size_t)row * D_MODEL;
        for (int c = tid; c < D_MODEL; c += 256) {
            const float* w = Wq + (size_t)c * D_MODEL;
            float acc = bq[c];
            for (int d = 0; d < D_MODEL; ++d) acc += xrow[d] * w[d];
            q_row[c] = acc;
            accO[c] = 0.f;
        }
        if (tid < NUM_HEADS) { m_h[tid] = -INFINITY; l_h[tid] = 0.f; }
        __syncthreads();

        for (int t = 0; t < SEQ; ++t) {
            if (!mrow[t]) continue;
            const float* xt = x + ((size_t)b * SEQ + t) * D_MODEL;
            for (int c = tid; c < D_MODEL; c += 256) {
                const float* w = Wk + (size_t)c * D_MODEL;
                float acc = bk[c];
                for (int d = 0; d < D_MODEL; ++d) acc += xt[d] * w[d];
                k_row[c] = acc;
            }
            __syncthreads();
            if (tid < NUM_HEADS) {
                float sc = 0.f;
                for (int j = 0; j < D_K; ++j) sc += q_row[tid * D_K + j] * k_row[tid * D_K + j];
                sc *= 0.125f;
                float mnew = fmaxf(m_h[tid], sc);
                float alpha = expf(m_h[tid] - mnew);
                float p = expf(sc - mnew);
                l_h[tid] = l_h[tid] * alpha + p;
                m_h[tid] = mnew;
                alpha_h[tid] = alpha;
                p_h[tid] = p;
            }
            __syncthreads();
            const float* vt = v + ((size_t)b * SEQ + t) * D_MODEL;
            for (int c = tid; c < D_MODEL; c += 256) {
                int h = c >> 6;
                accO[c] = accO[c] * alpha_h[h] + p_h[h] * vt[c];
            }
            __syncthreads();
        }
        for (int c = tid; c < D_MODEL; c += 256) {
            int h = c >> 6, j = c & 63;
            out[(((size_t)(b * NUM_HEADS + h)) * SEQ + s) * D_K + j] = accO[c] / l_h[h];
        }
        __syncthreads();
    }
}

extern "C" void kernel_launch(void* const* d_in, const int* in_sizes, int n_in,
                              void* d_out, int out_size, void* d_ws, size_t ws_size,
                              hipStream_t stream) {
    const float* x  = (const float*)d_in[0];
    const float* Wq = (const float*)d_in[1];
    const float* bq = (const float*)d_in[2];
    const float* Wk = (const float*)d_in[3];
    const float* bk = (const float*)d_in[4];
    const float* Wv = (const float*)d_in[5];
    const float* bv = (const float*)d_in[6];
    float* out = (float*)d_out;

    // workspace: xn bf16 (8MB) | Wvb bf16 (2MB) | v fp32 (16MB) | norms (16KB) | cnt (16KB)
    unsigned short* xn  = (unsigned short*)d_ws;
    unsigned short* Wvb = xn + (size_t)NROWS * D_MODEL;
    float* v     = (float*)(Wvb + (size_t)D_MODEL * D_MODEL);
    float* norms = v + (size_t)NROWS * D_MODEL;
    int* cnt     = (int*)(norms + NROWS);

    // L1: 4096 row-normalize blocks + 1024 Wv-cast blocks
    k_prep<<<NROWS + D_MODEL * D_MODEL / 1024, 256, 0, stream>>>(x, Wv, xn, Wvb, norms, cnt);

    // L2: 1024 vproj blocks + 1056 sim blocks
    k_main<<<GRID, 256, 0, stream>>>(xn, Wvb, bv, norms, v, cnt, out);

    // L3: fix non-singleton rows (cold)
    k_fix<<<NROWS / 256, 256, 0, stream>>>(x, Wq, bq, Wk, bk, v, xn, cnt, out);
}